// Round 12
// baseline (160.173 us; speedup 1.0000x reference)
//
#include <hip/hip_runtime.h>
#include <math.h>

#define S_ 2048
#define NH 8
#define DH 64
#define LP 72         // bf16 LDS row pitch: 144 B = 9*16 B -> b128-aligned

typedef __attribute__((ext_vector_type(8))) short short8;   // 8 x bf16 (4 VGPRs)
typedef __attribute__((ext_vector_type(4))) float f32x4;    // MFMA accumulator
typedef unsigned short ushort_t;

__device__ __forceinline__ short bf16r(float x) {   // RNE float->bf16
    union { float f; unsigned u; } v; v.f = x;
    unsigned r = v.u + 0x7fffu + ((v.u >> 16) & 1u);
    return (short)(r >> 16);
}
__device__ __forceinline__ float b2f(ushort_t h) {  // bf16->float
    union { float f; unsigned u; } v; v.u = ((unsigned)h) << 16; return v.f;
}

// ---------------------------------------------------------------------------
// Kernel 0: prep.  z<4: WT[n][k] = bf16(W[k][n]) (LDS-tiled 64x64).
// z==4: pos table bf16; rows 257..383 zero.
// z==5: xbar[b][e] = mean_s x[b,s,e]  (fp32) — feeds the linear vmean trick:
//       mean_s(x@Wv+bv) = xbar@Wv + bv  (computed in qkv's spare blocks).
// ---------------------------------------------------------------------------
__global__ __launch_bounds__(256) void prep_kernel(
    const float* __restrict__ x,
    const float* __restrict__ Wq, const float* __restrict__ Wk,
    const float* __restrict__ Wv, const float* __restrict__ Wkr,
    ushort_t* __restrict__ WTq, ushort_t* __restrict__ WTk,
    ushort_t* __restrict__ WTv, ushort_t* __restrict__ WTkr,
    ushort_t* __restrict__ pos, float* __restrict__ xbar)
{
    const int widx = blockIdx.z;
    const int t = threadIdx.x;
    __shared__ __align__(16) ushort_t T[64][72];

    if (widx == 4) {
        const int base = blockIdx.y * 8 + blockIdx.x;    // 0..63
        const float C = -0.051905126482615036f;          // -log2(10000)/256
        const int f = t;
#pragma unroll
        for (int rep = 0; rep < 6; ++rep) {
            const int r = base + rep * 64;               // 0..383
            unsigned pk = 0;
            if (r <= 256) {
                float ang = (float)r * exp2f(C * (float)f);
                unsigned s = (unsigned)(ushort_t)bf16r(sinf(ang));
                unsigned c = (unsigned)(ushort_t)bf16r(cosf(ang));
                pk = s | (c << 16);
            }
            ((unsigned*)pos)[(size_t)r * 256 + f] = pk;
        }
        return;
    }
    if (widx == 5) {
        if (blockIdx.y >= 2) return;
        const int b = blockIdx.y, e0 = blockIdx.x * 64;
        const int el = t & 63, stripe = t >> 6;
        const float* xs = &x[((size_t)b * S_ + stripe * 512) * 512 + e0 + el];
        float sum = 0.f;
        for (int s = 0; s < 512; ++s) sum += xs[(size_t)s * 512];
        float* sc = (float*)T;
        sc[stripe * 64 + el] = sum;
        __syncthreads();
        if (t < 64)
            xbar[b * 512 + e0 + t] =
                (sc[t] + sc[64 + t] + sc[128 + t] + sc[192 + t]) * (1.0f / 2048.f);
        return;
    }
    const float* W = (widx == 0) ? Wq : (widx == 1) ? Wk : (widx == 2) ? Wv : Wkr;
    ushort_t* WT   = (widx == 0) ? WTq : (widx == 1) ? WTk : (widx == 2) ? WTv : WTkr;
    const int k0 = blockIdx.x * 64, n0 = blockIdx.y * 64;
    const int srow = t >> 2, sc0 = (t & 3) * 16;
    const float* src = &W[(size_t)(k0 + srow) * 512 + n0 + sc0];
#pragma unroll
    for (int u = 0; u < 16; ++u) T[sc0 + u][srow] = (ushort_t)bf16r(src[u]);
    __syncthreads();
    ushort_t* dst = &WT[(size_t)(n0 + srow) * 512 + k0 + sc0];
    *(short8*)dst       = *(const short8*)&T[srow][sc0];
    *(short8*)(dst + 8) = *(const short8*)&T[srow][sc0 + 8];
}

// ---------------------------------------------------------------------------
// Kernel 1: fused QKV (+krel +vmean) GEMM via bf16 MFMA.  Grid (32, 25).
// by>>3 = 0: qcon/qrel; 1: k; 2: V^T (A=WTv, B=x -> coalesced vT stores);
// by==24, bx<24: krel = pos @ Wkr; bx>=24: vmean = xbar@WTv + bv (8 blocks).
// ---------------------------------------------------------------------------
__global__ __launch_bounds__(256) void qkv_gemm(
    const float* __restrict__ x,
    const ushort_t* __restrict__ WTq, const ushort_t* __restrict__ WTk,
    const ushort_t* __restrict__ WTv,
    const ushort_t* __restrict__ pos, const ushort_t* __restrict__ WTkr,
    const float* __restrict__ xbar,
    const float* __restrict__ b_con, const float* __restrict__ b_rel,
    const float* __restrict__ bv,
    ushort_t* __restrict__ qcon, ushort_t* __restrict__ qrel,
    ushort_t* __restrict__ kout, ushort_t* __restrict__ vT,
    ushort_t* __restrict__ krel, float* __restrict__ vmean)
{
    const int widx = blockIdx.y >> 3;
    const int tid = threadIdx.x, lane = tid & 63, w = tid >> 6;
    const int quad = lane >> 4, l16 = lane & 15;

    __shared__ __align__(16) ushort_t A_lds[128][40];
    __shared__ __align__(16) ushort_t B_lds[64][40];

    f32x4 acc[2][4];
#pragma unroll
    for (int mt = 0; mt < 2; ++mt)
#pragma unroll
        for (int nt = 0; nt < 4; ++nt) acc[mt][nt] = (f32x4){0.f, 0.f, 0.f, 0.f};

    const int arow = tid >> 1, ak0 = (tid & 1) * 16;
    const int brow = tid >> 2, bk0 = (tid & 3) * 8;

    if (widx < 2) {
        const int m0 = blockIdx.x * 128;
        const int n0 = (blockIdx.y & 7) * 64;
        const ushort_t* WT = (widx == 0) ? WTq : WTk;

        for (int k0 = 0; k0 < 512; k0 += 32) {
            const float* xs = &x[(size_t)(m0 + arow) * 512 + k0 + ak0];
            ushort_t t16[16];
#pragma unroll
            for (int u = 0; u < 16; ++u) t16[u] = (ushort_t)bf16r(xs[u]);
            *(short8*)&A_lds[arow][ak0]     = *(short8*)&t16[0];
            *(short8*)&A_lds[arow][ak0 + 8] = *(short8*)&t16[8];
            *(short8*)&B_lds[brow][bk0] =
                *(const short8*)&WT[(size_t)(n0 + brow) * 512 + k0 + bk0];
            __syncthreads();
            short8 a0 = *(const short8*)&A_lds[w * 32 + l16][quad * 8];
            short8 a1 = *(const short8*)&A_lds[w * 32 + 16 + l16][quad * 8];
#pragma unroll
            for (int nt = 0; nt < 4; ++nt) {
                short8 bb = *(const short8*)&B_lds[nt * 16 + l16][quad * 8];
                acc[0][nt] = __builtin_amdgcn_mfma_f32_16x16x32_bf16(a0, bb, acc[0][nt], 0, 0, 0);
                acc[1][nt] = __builtin_amdgcn_mfma_f32_16x16x32_bf16(a1, bb, acc[1][nt], 0, 0, 0);
            }
            __syncthreads();
        }

#pragma unroll
        for (int nt = 0; nt < 4; ++nt) {
            const int col = n0 + nt * 16 + l16;
            float bc = 0.f, br = 0.f;
            if (widx == 0) { bc = b_con[col]; br = b_rel[col]; }
#pragma unroll
            for (int mt = 0; mt < 2; ++mt) {
#pragma unroll
                for (int reg = 0; reg < 4; ++reg) {
                    const size_t m = (size_t)(m0 + w * 32 + mt * 16 + quad * 4 + reg);
                    const float val = acc[mt][nt][reg];
                    if (widx == 0) {
                        qcon[m * 512 + col] = (ushort_t)bf16r((val + bc) * 0.125f);
                        qrel[m * 512 + col] = (ushort_t)bf16r((val + br) * 0.125f);
                    } else {
                        kout[m * 512 + col] = (ushort_t)bf16r(val);
                    }
                }
            }
        }
    } else if (widx == 2) {
        // ---- V transposed mode ----
        const int vb = (blockIdx.y & 7) * 32 + blockIdx.x;   // 0..255
        const int m0d = (vb & 3) * 128;                      // d tile
        const int n0j = (vb >> 2) * 64;                      // seq tile

        for (int k0 = 0; k0 < 512; k0 += 32) {
            *(short8*)&A_lds[arow][ak0] =
                *(const short8*)&WTv[(size_t)(m0d + arow) * 512 + k0 + ak0];
            *(short8*)&A_lds[arow][ak0 + 8] =
                *(const short8*)&WTv[(size_t)(m0d + arow) * 512 + k0 + ak0 + 8];
            const float* xs = &x[(size_t)(n0j + brow) * 512 + k0 + bk0];
            ushort_t t8[8];
#pragma unroll
            for (int u = 0; u < 8; ++u) t8[u] = (ushort_t)bf16r(xs[u]);
            *(short8*)&B_lds[brow][bk0] = *(short8*)&t8[0];
            __syncthreads();
            short8 a0 = *(const short8*)&A_lds[w * 32 + l16][quad * 8];
            short8 a1 = *(const short8*)&A_lds[w * 32 + 16 + l16][quad * 8];
#pragma unroll
            for (int nt = 0; nt < 4; ++nt) {
                short8 bb = *(const short8*)&B_lds[nt * 16 + l16][quad * 8];
                acc[0][nt] = __builtin_amdgcn_mfma_f32_16x16x32_bf16(a0, bb, acc[0][nt], 0, 0, 0);
                acc[1][nt] = __builtin_amdgcn_mfma_f32_16x16x32_bf16(a1, bb, acc[1][nt], 0, 0, 0);
            }
            __syncthreads();
        }

        const int b = n0j >> 11;
#pragma unroll
        for (int mt = 0; mt < 2; ++mt) {
#pragma unroll
            for (int reg = 0; reg < 4; ++reg) {
                const int d = m0d + w * 32 + mt * 16 + quad * 4 + reg;  // 0..511
                const int n = d >> 6, dd = d & 63;
                const float bvv = bv[d];
#pragma unroll
                for (int nt = 0; nt < 4; ++nt) {
                    const int s = (n0j + nt * 16 + l16) & 2047;
                    vT[((size_t)((b * NH + n) * 64 + dd)) * 2048 + s] =
                        (ushort_t)bf16r(acc[mt][nt][reg] + bvv);
                }
            }
        }
    } else if (blockIdx.x < 24) {
        // ---- krel mode: krel = pos @ Wkr ----
        const int m0 = (blockIdx.x >> 3) * 128;              // 0..255
        const int n0 = (blockIdx.x & 7) * 64;

        for (int k0 = 0; k0 < 512; k0 += 32) {
            const ushort_t* ps = &pos[(size_t)(m0 + arow) * 512 + k0 + ak0];
            *(short8*)&A_lds[arow][ak0]     = *(const short8*)ps;
            *(short8*)&A_lds[arow][ak0 + 8] = *(const short8*)(ps + 8);
            *(short8*)&B_lds[brow][bk0] =
                *(const short8*)&WTkr[(size_t)(n0 + brow) * 512 + k0 + bk0];
            __syncthreads();
            short8 a0 = *(const short8*)&A_lds[w * 32 + l16][quad * 8];
            short8 a1 = *(const short8*)&A_lds[w * 32 + 16 + l16][quad * 8];
#pragma unroll
            for (int nt = 0; nt < 4; ++nt) {
                short8 bb = *(const short8*)&B_lds[nt * 16 + l16][quad * 8];
                acc[0][nt] = __builtin_amdgcn_mfma_f32_16x16x32_bf16(a0, bb, acc[0][nt], 0, 0, 0);
                acc[1][nt] = __builtin_amdgcn_mfma_f32_16x16x32_bf16(a1, bb, acc[1][nt], 0, 0, 0);
            }
            __syncthreads();
        }

#pragma unroll
        for (int nt = 0; nt < 4; ++nt) {
            const int col = n0 + nt * 16 + l16;
#pragma unroll
            for (int mt = 0; mt < 2; ++mt)
#pragma unroll
                for (int reg = 0; reg < 4; ++reg) {
                    const size_t m = (size_t)(m0 + w * 32 + mt * 16 + quad * 4 + reg);
                    krel[m * 512 + col] = (ushort_t)bf16r(acc[mt][nt][reg]);
                }
        }
    } else {
        // ---- vmean mode (8 blocks): vmean[b][d] = xbar[b] . WTv[d] + bv[d] ----
        const int d0 = (blockIdx.x - 24) * 64;
        const int dl = tid & 63, qtr = tid >> 6;
        const ushort_t* wrow = &WTv[(size_t)(d0 + dl) * 512 + qtr * 128];
        const float* xb0 = &xbar[qtr * 128];
        const float* xb1 = &xbar[512 + qtr * 128];
        float pa = 0.f, pb = 0.f;
        for (int k8 = 0; k8 < 16; ++k8) {
            short8 wv8 = *(const short8*)(wrow + k8 * 8);
#pragma unroll
            for (int u = 0; u < 8; ++u) {
                float wv = b2f((ushort_t)wv8[u]);
                pa += xb0[k8 * 8 + u] * wv;
                pb += xb1[k8 * 8 + u] * wv;
            }
        }
        float* sc = (float*)A_lds;    // 10240 B >= 512 floats
        sc[(qtr * 64 + dl) * 2 + 0] = pa;
        sc[(qtr * 64 + dl) * 2 + 1] = pb;
        __syncthreads();
        if (tid < 128) {
            const int bb = tid >> 6, dd = tid & 63;
            float s = sc[(dd) * 2 + bb] + sc[(64 + dd) * 2 + bb]
                    + sc[(128 + dd) * 2 + bb] + sc[(192 + dd) * 2 + bb];
            vmean[(size_t)bb * 512 + d0 + dd] = s + bv[d0 + dd];
        }
    }
}

// ---------------------------------------------------------------------------
// Kernel 2: banded attention via bf16 MFMA, batched softmax without max
// subtraction.  Round-12: rel_gemm is FUSED — each block computes its own
// 32x257 R-band into LDS upfront (5 krel chunks x 8 MFMAs; krel is 384 KB,
// L2-resident).  Each R value was consumed exactly once, so materializing R
// in HBM (17 MB write + scattered read + one dispatch) was pure overhead.
// qrel tile is staged into p_lds (overwritten by p in the main loop).
// LDS 43.5 KB -> 3 blocks/CU.  Main loop keeps the round-11 register
// prefetch of k/vT (rolled loop, explicit cur/next sets).
// ---------------------------------------------------------------------------
__global__ __launch_bounds__(128) void attn_kernel(
    const ushort_t* __restrict__ qcon, const ushort_t* __restrict__ qrel,
    const ushort_t* __restrict__ krel, const ushort_t* __restrict__ kbuf,
    const ushort_t* __restrict__ vT, const float* __restrict__ vmean,
    const int* __restrict__ xlen_p, float* __restrict__ out)
{
    const int bx = blockIdx.x;
    const int tile = ((bx & 7) << 3) | (bx >> 3);   // XCD swizzle
    const int n = blockIdx.y, b = blockIdx.z;
    const int i0 = tile * 32;
    const int tid = threadIdx.x, lane = tid & 63, w = tid >> 6;
    const int quad = lane >> 4, l16 = lane & 15;
    const int xlen = xlen_p[b];

    __shared__ __align__(16) ushort_t q_lds[32][LP];
    __shared__ __align__(16) ushort_t k_lds[64][LP];
    __shared__ __align__(16) ushort_t vT_lds[64][LP];
    __shared__ __align__(16) ushort_t p_lds[32][LP];
    __shared__ __align__(16) ushort_t Rb[32][264];

    // stage qcon -> q_lds, qrel -> p_lds (p_lds reused for p after Rband phase)
    {
        const int qr = tid >> 2, qc = (tid & 3) * 16;
        const ushort_t* qs = &qcon[((size_t)b * S_ + i0 + qr) * 512 + n * 64 + qc];
        const ushort_t* rs = &qrel[((size_t)b * S_ + i0 + qr) * 512 + n * 64 + qc];
        *(short8*)&q_lds[qr][qc]     = *(const short8*)qs;
        *(short8*)&q_lds[qr][qc + 8] = *(const short8*)(qs + 8);
        *(short8*)&p_lds[qr][qc]     = *(const short8*)rs;
        *(short8*)&p_lds[qr][qc + 8] = *(const short8*)(rs + 8);
    }

    const int srow = tid >> 1, sc0 = (tid & 1) * 32;

    // ---- Rband phase: Rb[row][r] = qrel_tile . krel[r]  (r in [0,256]) ----
#pragma unroll 1
    for (int rc = 0; rc < 5; ++rc) {
        __syncthreads();   // staging visible (rc==0) / prev MFMA k_lds reads done
        {
            const ushort_t* ksrc = &krel[(size_t)(rc * 64 + srow) * 512 + n * 64 + sc0];
#pragma unroll
            for (int u = 0; u < 4; ++u)
                *(short8*)&k_lds[srow][sc0 + u * 8] = *(const short8*)(ksrc + u * 8);
        }
        __syncthreads();
        short8 ar0 = *(const short8*)&p_lds[w * 16 + l16][quad * 8];
        short8 ar1 = *(const short8*)&p_lds[w * 16 + l16][quad * 8 + 32];
#pragma unroll
        for (int nt = 0; nt < 4; ++nt) {
            short8 bk0 = *(const short8*)&k_lds[nt * 16 + l16][quad * 8];
            short8 bk1 = *(const short8*)&k_lds[nt * 16 + l16][quad * 8 + 32];
            f32x4 s = (f32x4){0.f, 0.f, 0.f, 0.f};
            s = __builtin_amdgcn_mfma_f32_16x16x32_bf16(ar0, bk0, s, 0, 0, 0);
            s = __builtin_amdgcn_mfma_f32_16x16x32_bf16(ar1, bk1, s, 0, 0, 0);
            const int r = rc * 64 + nt * 16 + l16;
            if (r <= 256) {
#pragma unroll
                for (int reg = 0; reg < 4; ++reg)
                    Rb[w * 16 + quad * 4 + reg][r] = (ushort_t)bf16r(s[reg]);
            }
        }
    }

    f32x4 Oa[4];
#pragma unroll
    for (int nt = 0; nt < 4; ++nt) Oa[nt] = (f32x4){0.f, 0.f, 0.f, 0.f};
    float lpart[4] = {};

    const size_t vTbase = (size_t)((b * NH + n) * 64) * 2048;
    const short8 z8 = {0, 0, 0, 0, 0, 0, 0, 0};

    short8 kr[4], vr[4], kn[4], vn[4];

    auto issue = [&](int c, short8* kd, short8* vd) {
        const int jc0 = i0 - 256 + c * 64;
        const int jg = jc0 + srow;
        const bool okk = (jg >= 0);
        const ushort_t* ks = &kbuf[((size_t)b * S_ + jg) * 512 + n * 64 + sc0];
        const ushort_t* vs = &vT[vTbase + (size_t)srow * 2048 + jc0 + sc0];
#pragma unroll
        for (int u = 0; u < 4; ++u) {
            kd[u] = okk ? *(const short8*)(ks + u * 8) : z8;
            const bool okv = (jc0 + sc0 + u * 8) >= 0;
            vd[u] = okv ? *(const short8*)(vs + u * 8) : z8;
        }
    };

    issue(0, kr, vr);

#pragma unroll 1
    for (int c = 0; c < 5; ++c) {
        const int jc0 = i0 - 256 + c * 64;
        __syncthreads();   // Rband done (c==0) / prev-chunk PV reads done
#pragma unroll
        for (int u = 0; u < 4; ++u) {
            *(short8*)&k_lds[srow][sc0 + u * 8]  = kr[u];
            *(short8*)&vT_lds[srow][sc0 + u * 8] = vr[u];
        }
        if (c < 4) issue(c + 1, kn, vn);
        __syncthreads();

        // ---- QK ----
        short8 aq0 = *(const short8*)&q_lds[w * 16 + l16][quad * 8];
        short8 aq1 = *(const short8*)&q_lds[w * 16 + l16][quad * 8 + 32];
        f32x4 Sacc[4];
#pragma unroll
        for (int jt = 0; jt < 4; ++jt) {
            short8 bk0 = *(const short8*)&k_lds[jt * 16 + l16][quad * 8];
            short8 bk1 = *(const short8*)&k_lds[jt * 16 + l16][quad * 8 + 32];
            f32x4 s = (f32x4){0.f, 0.f, 0.f, 0.f};
            s = __builtin_amdgcn_mfma_f32_16x16x32_bf16(aq0, bk0, s, 0, 0, 0);
            s = __builtin_amdgcn_mfma_f32_16x16x32_bf16(aq1, bk1, s, 0, 0, 0);
            Sacc[jt] = s;
        }

        // ---- mask + rel bias (from LDS Rband) + exp; p -> LDS bf16 ----
#pragma unroll
        for (int jt = 0; jt < 4; ++jt) {
#pragma unroll
            for (int reg = 0; reg < 4; ++reg) {
                const int row = w * 16 + quad * 4 + reg;
                const int i = i0 + row;
                const int j = jc0 + jt * 16 + l16;
                const int r = i - j;
                const bool valid = (j >= 0) && (j < xlen) && (r >= 0) && (r <= 256);
                const int rcl = min(max(r, 0), 256);
                float rvv = b2f(Rb[row][rcl]);
                float e = valid ? __expf(Sacc[jt][reg] + rvv) : 0.f;
                lpart[reg] += e;
                p_lds[row][jt * 16 + l16] = (ushort_t)bf16r(e);
            }
        }
        __syncthreads();

        // ---- PV ----
        short8 ap0 = *(const short8*)&p_lds[w * 16 + l16][quad * 8];
        short8 ap1 = *(const short8*)&p_lds[w * 16 + l16][quad * 8 + 32];
#pragma unroll
        for (int nt = 0; nt < 4; ++nt) {
            short8 bv0 = *(const short8*)&vT_lds[nt * 16 + l16][quad * 8];
            short8 bv1 = *(const short8*)&vT_lds[nt * 16 + l16][quad * 8 + 32];
            Oa[nt] = __builtin_amdgcn_mfma_f32_16x16x32_bf16(ap0, bv0, Oa[nt], 0, 0, 0);
            Oa[nt] = __builtin_amdgcn_mfma_f32_16x16x32_bf16(ap1, bv1, Oa[nt], 0, 0, 0);
        }

#pragma unroll
        for (int u = 0; u < 4; ++u) { kr[u] = kn[u]; vr[u] = vn[u]; }
    }

#pragma unroll
    for (int reg = 0; reg < 4; ++reg) {
#pragma unroll
        for (int off = 1; off < 16; off <<= 1)
            lpart[reg] += __shfl_xor(lpart[reg], off, 64);
    }

#pragma unroll
    for (int reg = 0; reg < 4; ++reg) {
        const int i = i0 + w * 16 + quad * 4 + reg;
        const bool dead = (i >= xlen + 256);
        const float linv = 1.0f / lpart[reg];
#pragma unroll
        for (int nt = 0; nt < 4; ++nt) {
            const int d = n * 64 + nt * 16 + l16;
            float val = dead ? vmean[(size_t)b * 512 + d] : Oa[nt][reg] * linv;
            out[((size_t)b * S_ + i) * 512 + d] = val;
        }
    }
}

// ---------------------------------------------------------------------------
extern "C" void kernel_launch(void* const* d_in, const int* in_sizes, int n_in,
                              void* d_out, int out_size, void* d_ws, size_t ws_size,
                              hipStream_t stream) {
    const float* x     = (const float*)d_in[0];
    const float* Wq    = (const float*)d_in[1];
    const float* b_con = (const float*)d_in[2];
    const float* b_rel = (const float*)d_in[3];
    const float* Wk    = (const float*)d_in[4];
    const float* Wkr   = (const float*)d_in[5];
    const float* Wv    = (const float*)d_in[6];
    const float* bv    = (const float*)d_in[7];
    const int*   xlen  = (const int*)d_in[8];
    float* out = (float*)d_out;

    float* ws = (float*)d_ws;
    float* vmean = ws;                       // 1024 fp32
    float* xbar  = vmean + 1024;             // 1024 fp32
    ushort_t* ub   = (ushort_t*)(xbar + 1024);
    ushort_t* qcon = ub;                     // 4096*512 bf16
    ushort_t* kbuf = qcon + 2097152;
    ushort_t* vT   = kbuf + 2097152;         // 1024 x 2048 bf16
    ushort_t* qrel = vT   + 2097152;
    ushort_t* krel = qrel + 2097152;         // 384*512 bf16
    ushort_t* pos  = krel + 196608;          // 384*512 bf16
    ushort_t* WTq  = pos  + 196608;          // 512*512 bf16 each
    ushort_t* WTk  = WTq + 262144;
    ushort_t* WTv  = WTk + 262144;
    ushort_t* WTkr = WTv + 262144;

    prep_kernel<<<dim3(8, 8, 6), 256, 0, stream>>>(x, Wq, Wk, Wv, Wkr,
                                                   WTq, WTk, WTv, WTkr, pos, xbar);
    qkv_gemm<<<dim3(32, 25), 256, 0, stream>>>(x, WTq, WTk, WTv, pos, WTkr, xbar,
                                               b_con, b_rel, bv,
                                               qcon, qrel, kbuf, vT, krel, vmean);
    attn_kernel<<<dim3(64, 8, 2), 128, 0, stream>>>(qcon, qrel, krel, kbuf, vT,
                                                    vmean, xlen, out);
}

// Round 13
// 146.250 us; speedup vs baseline: 1.0952x; 1.0952x over previous
//
#include <hip/hip_runtime.h>
#include <math.h>

#define S_ 2048
#define NH 8
#define DH 64
#define RSTRIDE 264   // padded row stride for R (r in [0,256] meaningful)
#define LP 72         // bf16 LDS row pitch: 144 B = 9*16 B -> b128-aligned

typedef __attribute__((ext_vector_type(8))) short short8;   // 8 x bf16 (4 VGPRs)
typedef __attribute__((ext_vector_type(4))) float f32x4;    // MFMA accumulator
typedef unsigned short ushort_t;

__device__ __forceinline__ short bf16r(float x) {   // RNE float->bf16
    union { float f; unsigned u; } v; v.f = x;
    unsigned r = v.u + 0x7fffu + ((v.u >> 16) & 1u);
    return (short)(r >> 16);
}
__device__ __forceinline__ float b2f(ushort_t h) {  // bf16->float
    union { float f; unsigned u; } v; v.u = ((unsigned)h) << 16; return v.f;
}

// ---------------------------------------------------------------------------
// Kernel 0: prep.  z<4: WT[n][k] = bf16(W[k][n]) (LDS-tiled 64x64).
// z==4: pos table bf16; rows 257..383 zero.
// ---------------------------------------------------------------------------
__global__ __launch_bounds__(256) void prep_kernel(
    const float* __restrict__ Wq, const float* __restrict__ Wk,
    const float* __restrict__ Wv, const float* __restrict__ Wkr,
    ushort_t* __restrict__ WTq, ushort_t* __restrict__ WTk,
    ushort_t* __restrict__ WTv, ushort_t* __restrict__ WTkr,
    ushort_t* __restrict__ pos)
{
    const int widx = blockIdx.z;
    const int t = threadIdx.x;
    if (widx == 4) {
        const int base = blockIdx.y * 8 + blockIdx.x;    // 0..63
        const float C = -0.051905126482615036f;          // -log2(10000)/256
        const int f = t;
#pragma unroll
        for (int rep = 0; rep < 6; ++rep) {
            const int r = base + rep * 64;               // 0..383
            unsigned pk = 0;
            if (r <= 256) {
                float ang = (float)r * exp2f(C * (float)f);
                unsigned s = (unsigned)(ushort_t)bf16r(sinf(ang));
                unsigned c = (unsigned)(ushort_t)bf16r(cosf(ang));
                pk = s | (c << 16);
            }
            ((unsigned*)pos)[(size_t)r * 256 + f] = pk;
        }
        return;
    }
    const float* W = (widx == 0) ? Wq : (widx == 1) ? Wk : (widx == 2) ? Wv : Wkr;
    ushort_t* WT   = (widx == 0) ? WTq : (widx == 1) ? WTk : (widx == 2) ? WTv : WTkr;
    const int k0 = blockIdx.x * 64, n0 = blockIdx.y * 64;
    __shared__ __align__(16) ushort_t T[64][72];
    const int srow = t >> 2, sc0 = (t & 3) * 16;
    const float* src = &W[(size_t)(k0 + srow) * 512 + n0 + sc0];
#pragma unroll
    for (int u = 0; u < 16; ++u) T[sc0 + u][srow] = (ushort_t)bf16r(src[u]);
    __syncthreads();
    ushort_t* dst = &WT[(size_t)(n0 + srow) * 512 + k0 + sc0];
    *(short8*)dst       = *(const short8*)&T[srow][sc0];
    *(short8*)(dst + 8) = *(const short8*)&T[srow][sc0 + 8];
}

// ---------------------------------------------------------------------------
// Kernel 1: fused QKV (+krel) GEMM via bf16 MFMA.  Grid (32, 25).
// by>>3 = 0: qcon/qrel; 1: k; 2: V^T; by==24: krel = pos @ Wkr.
// Round-13: K-loop software-pipelined — next iter's A/B staged into raw
// registers (fp32, converted at ds_write time) while this iter's MFMAs run.
// Same trick that won round-11 in attn; removes the exposed load->ds_write
// latency of the classic 2-barrier K-loop.
// ---------------------------------------------------------------------------
__global__ __launch_bounds__(256) void qkv_gemm(
    const float* __restrict__ x,
    const ushort_t* __restrict__ WTq, const ushort_t* __restrict__ WTk,
    const ushort_t* __restrict__ WTv,
    const ushort_t* __restrict__ pos, const ushort_t* __restrict__ WTkr,
    const float* __restrict__ b_con, const float* __restrict__ b_rel,
    const float* __restrict__ bv,
    ushort_t* __restrict__ qcon, ushort_t* __restrict__ qrel,
    ushort_t* __restrict__ kout, ushort_t* __restrict__ vT,
    ushort_t* __restrict__ krel)
{
    const int widx = blockIdx.y >> 3;
    const int tid = threadIdx.x, lane = tid & 63, w = tid >> 6;
    const int quad = lane >> 4, l16 = lane & 15;

    __shared__ __align__(16) ushort_t A_lds[128][40];
    __shared__ __align__(16) ushort_t B_lds[64][40];

    f32x4 acc[2][4];
#pragma unroll
    for (int mt = 0; mt < 2; ++mt)
#pragma unroll
        for (int nt = 0; nt < 4; ++nt) acc[mt][nt] = (f32x4){0.f, 0.f, 0.f, 0.f};

    const int arow = tid >> 1, ak0 = (tid & 1) * 16;
    const int brow = tid >> 2, bk0 = (tid & 3) * 8;

    if (widx < 2) {
        const int m0 = blockIdx.x * 128;
        const int n0 = (blockIdx.y & 7) * 64;
        const ushort_t* WT = (widx == 0) ? WTq : WTk;

        float4 pa[4]; short8 pb;
        auto issueAB = [&](int k0) {
            const float* xs = &x[(size_t)(m0 + arow) * 512 + k0 + ak0];
            pa[0] = *(const float4*)(xs);
            pa[1] = *(const float4*)(xs + 4);
            pa[2] = *(const float4*)(xs + 8);
            pa[3] = *(const float4*)(xs + 12);
            pb = *(const short8*)&WT[(size_t)(n0 + brow) * 512 + k0 + bk0];
        };
        issueAB(0);

#pragma unroll 1
        for (int k0 = 0; k0 < 512; k0 += 32) {
            __syncthreads();   // prev iter's MFMA LDS reads done
            {
                const float* paf = (const float*)pa;
                ushort_t t16[16];
#pragma unroll
                for (int u = 0; u < 16; ++u) t16[u] = (ushort_t)bf16r(paf[u]);
                *(short8*)&A_lds[arow][ak0]     = *(short8*)&t16[0];
                *(short8*)&A_lds[arow][ak0 + 8] = *(short8*)&t16[8];
                *(short8*)&B_lds[brow][bk0] = pb;
            }
            if (k0 < 480) issueAB(k0 + 32);
            __syncthreads();
            short8 a0 = *(const short8*)&A_lds[w * 32 + l16][quad * 8];
            short8 a1 = *(const short8*)&A_lds[w * 32 + 16 + l16][quad * 8];
#pragma unroll
            for (int nt = 0; nt < 4; ++nt) {
                short8 bb = *(const short8*)&B_lds[nt * 16 + l16][quad * 8];
                acc[0][nt] = __builtin_amdgcn_mfma_f32_16x16x32_bf16(a0, bb, acc[0][nt], 0, 0, 0);
                acc[1][nt] = __builtin_amdgcn_mfma_f32_16x16x32_bf16(a1, bb, acc[1][nt], 0, 0, 0);
            }
        }

#pragma unroll
        for (int nt = 0; nt < 4; ++nt) {
            const int col = n0 + nt * 16 + l16;
            float bc = 0.f, br = 0.f;
            if (widx == 0) { bc = b_con[col]; br = b_rel[col]; }
#pragma unroll
            for (int mt = 0; mt < 2; ++mt) {
#pragma unroll
                for (int reg = 0; reg < 4; ++reg) {
                    const size_t m = (size_t)(m0 + w * 32 + mt * 16 + quad * 4 + reg);
                    const float val = acc[mt][nt][reg];
                    if (widx == 0) {
                        qcon[m * 512 + col] = (ushort_t)bf16r((val + bc) * 0.125f);
                        qrel[m * 512 + col] = (ushort_t)bf16r((val + br) * 0.125f);
                    } else {
                        kout[m * 512 + col] = (ushort_t)bf16r(val);
                    }
                }
            }
        }
    } else if (widx == 2) {
        // ---- V transposed mode: vT[d][j] = WTv[d] . x[j] + bv ----
        const int vb = (blockIdx.y & 7) * 32 + blockIdx.x;   // 0..255
        const int m0d = (vb & 3) * 128;                      // d tile
        const int n0j = (vb >> 2) * 64;                      // seq tile

        short8 paw[2]; float4 pxb[2];
        auto issueAB = [&](int k0) {
            const ushort_t* as = &WTv[(size_t)(m0d + arow) * 512 + k0 + ak0];
            paw[0] = *(const short8*)as;
            paw[1] = *(const short8*)(as + 8);
            const float* xs = &x[(size_t)(n0j + brow) * 512 + k0 + bk0];
            pxb[0] = *(const float4*)(xs);
            pxb[1] = *(const float4*)(xs + 4);
        };
        issueAB(0);

#pragma unroll 1
        for (int k0 = 0; k0 < 512; k0 += 32) {
            __syncthreads();
            {
                *(short8*)&A_lds[arow][ak0]     = paw[0];
                *(short8*)&A_lds[arow][ak0 + 8] = paw[1];
                const float* pxf = (const float*)pxb;
                ushort_t t8[8];
#pragma unroll
                for (int u = 0; u < 8; ++u) t8[u] = (ushort_t)bf16r(pxf[u]);
                *(short8*)&B_lds[brow][bk0] = *(short8*)&t8[0];
            }
            if (k0 < 480) issueAB(k0 + 32);
            __syncthreads();
            short8 a0 = *(const short8*)&A_lds[w * 32 + l16][quad * 8];
            short8 a1 = *(const short8*)&A_lds[w * 32 + 16 + l16][quad * 8];
#pragma unroll
            for (int nt = 0; nt < 4; ++nt) {
                short8 bb = *(const short8*)&B_lds[nt * 16 + l16][quad * 8];
                acc[0][nt] = __builtin_amdgcn_mfma_f32_16x16x32_bf16(a0, bb, acc[0][nt], 0, 0, 0);
                acc[1][nt] = __builtin_amdgcn_mfma_f32_16x16x32_bf16(a1, bb, acc[1][nt], 0, 0, 0);
            }
        }

        const int b = n0j >> 11;
#pragma unroll
        for (int mt = 0; mt < 2; ++mt) {
#pragma unroll
            for (int reg = 0; reg < 4; ++reg) {
                const int d = m0d + w * 32 + mt * 16 + quad * 4 + reg;  // 0..511
                const int n = d >> 6, dd = d & 63;
                const float bvv = bv[d];
#pragma unroll
                for (int nt = 0; nt < 4; ++nt) {
                    const int s = (n0j + nt * 16 + l16) & 2047;
                    vT[((size_t)((b * NH + n) * 64 + dd)) * 2048 + s] =
                        (ushort_t)bf16r(acc[mt][nt][reg] + bvv);
                }
            }
        }
    } else {
        // ---- krel mode (by == 24): krel = pos @ Wkr ----
        if (blockIdx.x >= 24) return;
        const int m0 = (blockIdx.x >> 3) * 128;              // 0..255
        const int n0 = (blockIdx.x & 7) * 64;

        short8 pA[2], pB;
        auto issueAB = [&](int k0) {
            const ushort_t* ps = &pos[(size_t)(m0 + arow) * 512 + k0 + ak0];
            pA[0] = *(const short8*)ps;
            pA[1] = *(const short8*)(ps + 8);
            pB = *(const short8*)&WTkr[(size_t)(n0 + brow) * 512 + k0 + bk0];
        };
        issueAB(0);

#pragma unroll 1
        for (int k0 = 0; k0 < 512; k0 += 32) {
            __syncthreads();
            *(short8*)&A_lds[arow][ak0]     = pA[0];
            *(short8*)&A_lds[arow][ak0 + 8] = pA[1];
            *(short8*)&B_lds[brow][bk0]     = pB;
            if (k0 < 480) issueAB(k0 + 32);
            __syncthreads();
            short8 a0 = *(const short8*)&A_lds[w * 32 + l16][quad * 8];
            short8 a1 = *(const short8*)&A_lds[w * 32 + 16 + l16][quad * 8];
#pragma unroll
            for (int nt = 0; nt < 4; ++nt) {
                short8 bb = *(const short8*)&B_lds[nt * 16 + l16][quad * 8];
                acc[0][nt] = __builtin_amdgcn_mfma_f32_16x16x32_bf16(a0, bb, acc[0][nt], 0, 0, 0);
                acc[1][nt] = __builtin_amdgcn_mfma_f32_16x16x32_bf16(a1, bb, acc[1][nt], 0, 0, 0);
            }
        }

#pragma unroll
        for (int nt = 0; nt < 4; ++nt) {
            const int col = n0 + nt * 16 + l16;
#pragma unroll
            for (int mt = 0; mt < 2; ++mt)
#pragma unroll
                for (int reg = 0; reg < 4; ++reg) {
                    const size_t m = (size_t)(m0 + w * 32 + mt * 16 + quad * 4 + reg);
                    krel[m * 512 + col] = (ushort_t)bf16r(acc[mt][nt][reg]);
                }
        }
    }
}

// ---------------------------------------------------------------------------
// Kernel 3: R[b,n,i,r] bf16 = qrel . krel  (scale in qrel).  Grid (17,8,2):
// tile<16 = GEMM (B chunks register-prefetched); tile==16 = vmean fold.
// ---------------------------------------------------------------------------
__global__ __launch_bounds__(256) void rel_gemm(
    const ushort_t* __restrict__ qrel, const ushort_t* __restrict__ krel,
    const ushort_t* __restrict__ vT, ushort_t* __restrict__ R,
    float* __restrict__ vmean)
{
    const int tile = blockIdx.x, n = blockIdx.y, b = blockIdx.z;
    const int tid = threadIdx.x, lane = tid & 63, w = tid >> 6;
    const int quad = lane >> 4, l16 = lane & 15;

    __shared__ __align__(16) ushort_t A_lds[128][LP];
    __shared__ __align__(16) ushort_t B_lds[64][LP];

    if (tile == 16) {
        // ---- vmean: rows (b*8+n)*64 + d of vT, mean over 2048 ----
        const int row = tid >> 2, seg = tid & 3;
        const ushort_t* src = &vT[((size_t)((b * NH + n) * 64 + row)) * 2048 + seg * 512];
        float sum = 0.f;
        for (int it = 0; it < 64; ++it) {
            short8 h = *(const short8*)(src + it * 8);
#pragma unroll
            for (int u = 0; u < 8; ++u) sum += b2f((ushort_t)h[u]);
        }
        float* scratch = (float*)A_lds;
        scratch[row * 4 + seg] = sum;
        __syncthreads();
        if (tid < 64) {
            float s = scratch[tid * 4] + scratch[tid * 4 + 1]
                    + scratch[tid * 4 + 2] + scratch[tid * 4 + 3];
            vmean[(size_t)b * 512 + n * 64 + tid] = s * (1.0f / (float)S_);
        }
        return;
    }

    const int i0 = tile * 128;
    {
        const int srow = tid >> 1, sc0 = (tid & 1) * 32;
        const ushort_t* src = &qrel[((size_t)b * S_ + i0 + srow) * 512 + n * 64 + sc0];
#pragma unroll
        for (int u = 0; u < 4; ++u)
            *(short8*)&A_lds[srow][sc0 + u * 8] = *(const short8*)(src + u * 8);
    }

    const size_t rbase = ((size_t)(b * NH + n) * S_ + i0) * RSTRIDE;
    const int srow2 = tid >> 2, sc2 = (tid & 3) * 16;

    short8 pb0, pb1;
    auto issueB = [&](int rc) {
        const ushort_t* src = &krel[(size_t)(rc * 64 + srow2) * 512 + n * 64 + sc2];
        pb0 = *(const short8*)src;
        pb1 = *(const short8*)(src + 8);
    };
    issueB(0);

#pragma unroll 1
    for (int rc = 0; rc < 5; ++rc) {
        __syncthreads();   // A visible (rc==0) / prev chunk's B reads done
        *(short8*)&B_lds[srow2][sc2]     = pb0;
        *(short8*)&B_lds[srow2][sc2 + 8] = pb1;
        if (rc < 4) issueB(rc + 1);
        __syncthreads();

        short8 a[2][2];
#pragma unroll
        for (int mt = 0; mt < 2; ++mt) {
            a[mt][0] = *(const short8*)&A_lds[w * 32 + mt * 16 + l16][quad * 8];
            a[mt][1] = *(const short8*)&A_lds[w * 32 + mt * 16 + l16][quad * 8 + 32];
        }
#pragma unroll
        for (int nt = 0; nt < 4; ++nt) {
            short8 b0 = *(const short8*)&B_lds[nt * 16 + l16][quad * 8];
            short8 b1 = *(const short8*)&B_lds[nt * 16 + l16][quad * 8 + 32];
            const int r = rc * 64 + nt * 16 + l16;
#pragma unroll
            for (int mt = 0; mt < 2; ++mt) {
                f32x4 s = (f32x4){0.f, 0.f, 0.f, 0.f};
                s = __builtin_amdgcn_mfma_f32_16x16x32_bf16(a[mt][0], b0, s, 0, 0, 0);
                s = __builtin_amdgcn_mfma_f32_16x16x32_bf16(a[mt][1], b1, s, 0, 0, 0);
                if (r < RSTRIDE) {
#pragma unroll
                    for (int reg = 0; reg < 4; ++reg) {
                        const int i = w * 32 + mt * 16 + quad * 4 + reg;
                        R[rbase + (size_t)i * RSTRIDE + r] = (ushort_t)bf16r(s[reg]);
                    }
                }
            }
        }
    }
}

// ---------------------------------------------------------------------------
// Kernel 5: banded attention via bf16 MFMA, batched softmax without max
// subtraction.  Round-11 structure (best): register prefetch of next chunk's
// k/vT/R, rolled loop, 27.6 KB LDS -> 5 blocks/CU.
// ---------------------------------------------------------------------------
__global__ __launch_bounds__(128) void attn_kernel(
    const ushort_t* __restrict__ qcon, const ushort_t* __restrict__ kbuf,
    const ushort_t* __restrict__ vT, const ushort_t* __restrict__ R,
    const float* __restrict__ vmean, const int* __restrict__ xlen_p,
    float* __restrict__ out)
{
    const int bx = blockIdx.x;
    const int tile = ((bx & 7) << 3) | (bx >> 3);   // XCD swizzle
    const int n = blockIdx.y, b = blockIdx.z;
    const int i0 = tile * 32;
    const int tid = threadIdx.x, lane = tid & 63, w = tid >> 6;
    const int quad = lane >> 4, l16 = lane & 15;
    const int xlen = xlen_p[b];

    __shared__ __align__(16) ushort_t q_lds[32][LP];
    __shared__ __align__(16) ushort_t k_lds[64][LP];
    __shared__ __align__(16) ushort_t vT_lds[64][LP];
    __shared__ __align__(16) ushort_t p_lds[32][LP];

    {
        const int qr = tid >> 2, qc = (tid & 3) * 16;
        const ushort_t* src = &qcon[((size_t)b * S_ + i0 + qr) * 512 + n * 64 + qc];
        *(short8*)&q_lds[qr][qc]     = *(const short8*)src;
        *(short8*)&q_lds[qr][qc + 8] = *(const short8*)(src + 8);
    }

    f32x4 Oa[4];
#pragma unroll
    for (int nt = 0; nt < 4; ++nt) Oa[nt] = (f32x4){0.f, 0.f, 0.f, 0.f};
    float lpart[4] = {};

    const size_t rrowB = (size_t)(b * NH + n) * S_ * RSTRIDE;
    const size_t vTbase = (size_t)((b * NH + n) * 64) * 2048;
    const int srow = tid >> 1, sc0 = (tid & 1) * 32;
    const short8 z8 = {0, 0, 0, 0, 0, 0, 0, 0};

    short8 kr[4], vr[4], kn[4], vn[4];
    ushort_t rc_[16], rn_[16];

    auto issue = [&](int c, short8* kd, short8* vd, ushort_t* rd) {
        const int jc0 = i0 - 256 + c * 64;
        const int jg = jc0 + srow;
        const bool okk = (jg >= 0);
        const ushort_t* ks = &kbuf[((size_t)b * S_ + jg) * 512 + n * 64 + sc0];
        const ushort_t* vs = &vT[vTbase + (size_t)srow * 2048 + jc0 + sc0];
#pragma unroll
        for (int u = 0; u < 4; ++u) {
            kd[u] = okk ? *(const short8*)(ks + u * 8) : z8;
            const bool okv = (jc0 + sc0 + u * 8) >= 0;
            vd[u] = okv ? *(const short8*)(vs + u * 8) : z8;
        }
#pragma unroll
        for (int jt = 0; jt < 4; ++jt) {
#pragma unroll
            for (int reg = 0; reg < 4; ++reg) {
                const int i = i0 + w * 16 + quad * 4 + reg;
                const int j = jc0 + jt * 16 + l16;
                const int r = i - j;
                const bool valid = (j >= 0) && (j < xlen) && (r >= 0) && (r <= 256);
                rd[jt * 4 + reg] = valid ? R[rrowB + (size_t)i * RSTRIDE + r]
                                         : (ushort_t)0;
            }
        }
    };

    issue(0, kr, vr, rc_);

#pragma unroll 1
    for (int c = 0; c < 5; ++c) {
        const int jc0 = i0 - 256 + c * 64;
        __syncthreads();   // prev-chunk PV reads of k/vT/p done
#pragma unroll
        for (int u = 0; u < 4; ++u) {
            *(short8*)&k_lds[srow][sc0 + u * 8]  = kr[u];
            *(short8*)&vT_lds[srow][sc0 + u * 8] = vr[u];
        }
        if (c < 4) issue(c + 1, kn, vn, rn_);
        __syncthreads();

        // ---- QK ----
        short8 aq0 = *(const short8*)&q_lds[w * 16 + l16][quad * 8];
        short8 aq1 = *(const short8*)&q_lds[w * 16 + l16][quad * 8 + 32];
        f32x4 Sacc[4];
#pragma unroll
        for (int jt = 0; jt < 4; ++jt) {
            short8 bk0 = *(const short8*)&k_lds[jt * 16 + l16][quad * 8];
            short8 bk1 = *(const short8*)&k_lds[jt * 16 + l16][quad * 8 + 32];
            f32x4 s = (f32x4){0.f, 0.f, 0.f, 0.f};
            s = __builtin_amdgcn_mfma_f32_16x16x32_bf16(aq0, bk0, s, 0, 0, 0);
            s = __builtin_amdgcn_mfma_f32_16x16x32_bf16(aq1, bk1, s, 0, 0, 0);
            Sacc[jt] = s;
        }

        // ---- mask + rel bias + exp; p -> LDS bf16 ----
#pragma unroll
        for (int jt = 0; jt < 4; ++jt) {
#pragma unroll
            for (int reg = 0; reg < 4; ++reg) {
                const int i = i0 + w * 16 + quad * 4 + reg;
                const int j = jc0 + jt * 16 + l16;
                const int r = i - j;
                const bool valid = (j >= 0) && (j < xlen) && (r >= 0) && (r <= 256);
                float e = valid ? __expf(Sacc[jt][reg] + b2f(rc_[jt * 4 + reg])) : 0.f;
                lpart[reg] += e;
                p_lds[w * 16 + quad * 4 + reg][jt * 16 + l16] = (ushort_t)bf16r(e);
            }
        }
        __syncthreads();

        // ---- PV ----
        short8 ap0 = *(const short8*)&p_lds[w * 16 + l16][quad * 8];
        short8 ap1 = *(const short8*)&p_lds[w * 16 + l16][quad * 8 + 32];
#pragma unroll
        for (int nt = 0; nt < 4; ++nt) {
            short8 bv0 = *(const short8*)&vT_lds[nt * 16 + l16][quad * 8];
            short8 bv1 = *(const short8*)&vT_lds[nt * 16 + l16][quad * 8 + 32];
            Oa[nt] = __builtin_amdgcn_mfma_f32_16x16x32_bf16(ap0, bv0, Oa[nt], 0, 0, 0);
            Oa[nt] = __builtin_amdgcn_mfma_f32_16x16x32_bf16(ap1, bv1, Oa[nt], 0, 0, 0);
        }

        // ---- rotate register sets ----
#pragma unroll
        for (int u = 0; u < 4; ++u) { kr[u] = kn[u]; vr[u] = vn[u]; }
#pragma unroll
        for (int u = 0; u < 16; ++u) rc_[u] = rn_[u];
    }

#pragma unroll
    for (int reg = 0; reg < 4; ++reg) {
#pragma unroll
        for (int off = 1; off < 16; off <<= 1)
            lpart[reg] += __shfl_xor(lpart[reg], off, 64);
    }

#pragma unroll
    for (int reg = 0; reg < 4; ++reg) {
        const int i = i0 + w * 16 + quad * 4 + reg;
        const bool dead = (i >= xlen + 256);
        const float linv = 1.0f / lpart[reg];
#pragma unroll
        for (int nt = 0; nt < 4; ++nt) {
            const int d = n * 64 + nt * 16 + l16;
            float val = dead ? vmean[(size_t)b * 512 + d] : Oa[nt][reg] * linv;
            out[((size_t)b * S_ + i) * 512 + d] = val;
        }
    }
}

// ---------------------------------------------------------------------------
extern "C" void kernel_launch(void* const* d_in, const int* in_sizes, int n_in,
                              void* d_out, int out_size, void* d_ws, size_t ws_size,
                              hipStream_t stream) {
    const float* x     = (const float*)d_in[0];
    const float* Wq    = (const float*)d_in[1];
    const float* b_con = (const float*)d_in[2];
    const float* b_rel = (const float*)d_in[3];
    const float* Wk    = (const float*)d_in[4];
    const float* Wkr   = (const float*)d_in[5];
    const float* Wv    = (const float*)d_in[6];
    const float* bv    = (const float*)d_in[7];
    const int*   xlen  = (const int*)d_in[8];
    float* out = (float*)d_out;

    float* ws = (float*)d_ws;
    float* vmean = ws;                       // 1024 fp32
    ushort_t* ub   = (ushort_t*)(vmean + 1024);
    ushort_t* R    = ub;                     // 2*8*2048*264 bf16
    ushort_t* qcon = R    + 8650752;         // 4096*512 bf16
    ushort_t* kbuf = qcon + 2097152;
    ushort_t* vT   = kbuf + 2097152;         // 1024 x 2048 bf16
    ushort_t* qrel = vT   + 2097152;
    ushort_t* krel = qrel + 2097152;         // 384*512 bf16
    ushort_t* pos  = krel + 196608;          // 384*512 bf16
    ushort_t* WTq  = pos  + 196608;          // 512*512 bf16 each
    ushort_t* WTk  = WTq + 262144;
    ushort_t* WTv  = WTk + 262144;
    ushort_t* WTkr = WTv + 262144;

    prep_kernel<<<dim3(8, 8, 5), 256, 0, stream>>>(Wq, Wk, Wv, Wkr,
                                                   WTq, WTk, WTv, WTkr, pos);
    qkv_gemm<<<dim3(32, 25), 256, 0, stream>>>(x, WTq, WTk, WTv, pos, WTkr,
                                               b_con, b_rel, bv,
                                               qcon, qrel, kbuf, vT, krel);
    rel_gemm<<<dim3(17, 8, 2), 256, 0, stream>>>(qrel, krel, vT, R, vmean);
    attn_kernel<<<dim3(64, 8, 2), 128, 0, stream>>>(qcon, kbuf, vT, R, vmean,
                                                    xlen, out);
}